// Round 5
// baseline (304.041 us; speedup 1.0000x reference)
//
#include <hip/hip_runtime.h>
#include <hip/hip_cooperative_groups.h>
#include <math.h>

namespace cg = cooperative_groups;

namespace {
constexpr int cB = 8, cS = 16, cP = 32, cN = 2048, cV = 2562;
constexpr int cK = 500;              // K_SAMPLE
constexpr int cJ = cS * cK;          // 8000 pred points per batch
constexpr int cJC = 32;              // j-chunks for global role (250 each)
constexpr int cJCH = cJ / cJC;       // 250
constexpr int cNC = 16;              // target-chunks for perslot role (128 each)
constexpr int cNCH = cN / cNC;       // 128
constexpr int cJPAD = 8192;
constexpr int cBN = cB * cN;         // 16384
constexpr int GRID = 768;            // 3 blocks/CU, co-resident (cooperative)
constexpr float FINF = 3.402823466e+38f;

// workspace layout (float offsets)
constexpr int OFF_PRED4 = 0;                         // cB*cJ*4 = 256000
constexpr int OFF_TGT4  = 256000;                    // cBN*4 = 65536
constexpr int OFF_VBAR  = 321536;                    // 4
constexpr int OFF_OBAR  = 321540;                    // 96
constexpr int OFF_SM    = 321664;                    // 128*288 = 36864
constexpr int OFF_SC    = 358528;                    // 384
constexpr int OFF_T3    = 358912;                    // 96*cBN = 1572864 (plane-major)
constexpr int OFF_PSP   = 1931776;                   // cB*cNC*cJPAD = 1048576
constexpr int OFF_GM    = 2980352;                   // 64
constexpr int OFF_PS    = 2980416;                   // 256
} // namespace

__device__ __forceinline__ float block_sum(float v, float* red, int tid) {
  red[tid] = v;
  __syncthreads();
  for (int s = 128; s > 0; s >>= 1) {
    if (tid < s) red[tid] += red[tid + s];
    __syncthreads();
  }
  return red[0];
}

// branchless sorted top-3 insert, 3 VALU ops (min + 2x med3); exact
__device__ __forceinline__ void top3_insert(float& t0, float& t1, float& t2, float d) {
  const float n1 = __builtin_amdgcn_fmed3f(t0, t1, d);
  const float n2 = __builtin_amdgcn_fmed3f(t1, t2, d);
  t0 = fminf(t0, d);
  t1 = n1;
  t2 = n2;
}

__global__ void __launch_bounds__(256, 3) k_mega(const float* __restrict__ scales,
                                                 const float* __restrict__ transforms,
                                                 const float* __restrict__ pw,
                                                 const float* __restrict__ offs,
                                                 const float* __restrict__ verts,
                                                 const float* __restrict__ target,
                                                 float* __restrict__ ws,
                                                 float* __restrict__ out) {
  cg::grid_group grid = cg::this_grid();
  const int blk = blockIdx.x;
  const int tid = threadIdx.x;
  __shared__ float4 sBuf[cJCH];       // 4000 B (perslot role uses first 128)
  __shared__ float red[256];
  __shared__ float sM[cP][9];
  __shared__ float sWT[cP][3];
  __shared__ float sC[3];
  __shared__ float scent[cB * cS * 3];

  // ================= phase 0: front =================
  if (blk <= cP) {
    // per-prototype mean offsets (+ mean vertex)
    const float* src = (blk < cP) ? (offs + blk * cV * 3) : verts;
    float acc0 = 0.f, acc1 = 0.f, acc2 = 0.f;
    for (int v = tid; v < cV; v += 256) {
      acc0 += src[v * 3 + 0];
      acc1 += src[v * 3 + 1];
      acc2 += src[v * 3 + 2];
    }
    float* dst = (blk < cP) ? (ws + OFF_OBAR + blk * 3) : (ws + OFF_VBAR);
    float a[3] = {acc0, acc1, acc2};
    for (int c = 0; c < 3; ++c) {
      float s = block_sum(a[c], red, tid);
      if (tid == 0) dst[c] = s / (float)cV;
      __syncthreads();
    }
  } else if (blk <= cP + 64) {
    // target float4 (x,y,z,|t|^2/2)
    const int idx = (blk - (cP + 1)) * 256 + tid;  // over cBN
    const float x = target[idx * 3 + 0];
    const float y = target[idx * 3 + 1];
    const float z = target[idx * 3 + 2];
    ((float4*)(ws + OFF_TGT4))[idx] =
        make_float4(x, y, z, 0.5f * fmaf(x, x, fmaf(y, y, z * z)));
  } else if (blk <= cP + 64 + cB * cS) {
    // pred float4 for one (b,s); persist sM / sC
    const int bs = blk - (cP + 65);  // 0..127
    if (tid < cP) {
      const int p = tid;
      const float* t = transforms + (bs * cP + p) * 6;
      const float w = pw[bs * cP + p];
      const float sc = scales[bs];
      const float a = t[3], b = t[4], c = t[5];
      const float ca = cosf(a), sa = sinf(a);
      const float cb = cosf(b), sb = sinf(b);
      const float cg_ = cosf(c), sg = sinf(c);
      const float f = w * sc;
      sM[p][0] = f * (cb * cg_);
      sM[p][1] = f * (-cb * sg);
      sM[p][2] = f * (sb);
      sM[p][3] = f * (ca * sg + sa * sb * cg_);
      sM[p][4] = f * (ca * cg_ - sa * sb * sg);
      sM[p][5] = f * (-sa * cb);
      sM[p][6] = f * (sa * sg - ca * sb * cg_);
      sM[p][7] = f * (sa * cg_ + ca * sb * sg);
      sM[p][8] = f * (ca * cb);
      sWT[p][0] = w * t[0];
      sWT[p][1] = w * t[1];
      sWT[p][2] = w * t[2];
    }
    __syncthreads();
    if (tid < 3) {
      float s = 0.f;
      for (int p = 0; p < cP; ++p) s += sWT[p][tid];
      sC[tid] = s;
    }
    __syncthreads();
    if (tid < cP * 9) ws[OFF_SM + bs * 288 + tid] = ((const float*)sM)[tid];
    if (tid < 3) ws[OFF_SC + bs * 3 + tid] = sC[tid];
    for (int k = tid; k < cK; k += 256) {
      const float x0 = verts[k * 3 + 0], x1 = verts[k * 3 + 1], x2 = verts[k * 3 + 2];
      float a0 = sC[0], a1 = sC[1], a2 = sC[2];
#pragma unroll 8
      for (int p = 0; p < cP; ++p) {
        const float* o = offs + (p * cV + k) * 3;
        const float d0 = x0 + o[0], d1 = x1 + o[1], d2 = x2 + o[2];
        a0 = fmaf(sM[p][0], d0, fmaf(sM[p][1], d1, fmaf(sM[p][2], d2, a0)));
        a1 = fmaf(sM[p][3], d0, fmaf(sM[p][4], d1, fmaf(sM[p][5], d2, a1)));
        a2 = fmaf(sM[p][6], d0, fmaf(sM[p][7], d1, fmaf(sM[p][8], d2, a2)));
      }
      ((float4*)(ws + OFF_PRED4))[bs * cK + k] =
          make_float4(a0, a1, a2, 0.5f * fmaf(a0, a0, fmaf(a1, a1, a2 * a2)));
    }
  }
  grid.sync();

  // ================= phase 1: distance passes =================
  if (blk % 3 == 0) {
    // global role: 250-pred LDS tile, 8 targets/thread, top-3 of s = hp - t.p
    const int g = blk / 3;          // 0..255
    const int b = g & 7;
    const int jc = g >> 3;          // 0..31
    const float4* pr = (const float4*)(ws + OFF_PRED4) + b * cJ + jc * cJCH;
    if (tid < cJCH) sBuf[tid] = pr[tid];
    __syncthreads();
    const float4* tg = (const float4*)(ws + OFF_TGT4) + b * cN;
    float4 t[8];
#pragma unroll
    for (int q = 0; q < 8; ++q) t[q] = tg[tid + q * 256];
    float a0[8], a1[8], a2[8];
#pragma unroll
    for (int q = 0; q < 8; ++q) { a0[q] = FINF; a1[q] = FINF; a2[q] = FINF; }
#pragma unroll 2
    for (int j = 0; j < cJCH; ++j) {
      const float4 p = sBuf[j];
#pragma unroll
      for (int q = 0; q < 8; ++q) {
        const float s =
            fmaf(-t[q].x, p.x, fmaf(-t[q].y, p.y, fmaf(-t[q].z, p.z, p.w)));
        top3_insert(a0[q], a1[q], a2[q], s);
      }
    }
    float* plane = ws + OFF_T3 + (jc * 3) * cBN;
#pragma unroll
    for (int q = 0; q < 8; ++q) {
      const int idx = b * cN + tid + q * 256;
      plane[0 * cBN + idx] = a0[q];
      plane[1 * cBN + idx] = a1[q];
      plane[2 * cBN + idx] = a2[q];
    }
  } else {
    // perslot role: 128-target LDS tile, 8 preds/thread, min of s = ht - p.t
    const int idxr = (blk / 3) * 2 + (blk % 3) - 1;  // 0..511
    const int jb = idxr & 3;
    const int nc = (idxr >> 2) & 15;
    const int b = idxr >> 6;
    const float4* tg = (const float4*)(ws + OFF_TGT4) + b * cN + nc * cNCH;
    if (tid < cNCH) sBuf[tid] = tg[tid];
    __syncthreads();
    const float4* pr = (const float4*)(ws + OFF_PRED4) + b * cJ;
    float px[8], py[8], pz[8];
    float m[8] = {FINF, FINF, FINF, FINF, FINF, FINF, FINF, FINF};
#pragma unroll
    for (int q = 0; q < 8; ++q) {
      int j = jb * 2048 + q * 256 + tid;
      j = (j < cJ) ? j : (cJ - 1);
      const float4 p = pr[j];
      px[q] = p.x; py[q] = p.y; pz[q] = p.z;
    }
#pragma unroll 2
    for (int n = 0; n < cNCH; ++n) {
      const float4 t = sBuf[n];
#pragma unroll
      for (int q = 0; q < 8; ++q) {
        const float s = fmaf(-px[q], t.x, fmaf(-py[q], t.y, fmaf(-pz[q], t.z, t.w)));
        m[q] = fminf(m[q], s);
      }
    }
    float* o = ws + OFF_PSP + (b * cNC + nc) * cJPAD + jb * 2048 + tid;
#pragma unroll
    for (int q = 0; q < 8; ++q) o[q * 256] = m[q];
  }
  grid.sync();

  // ================= phase 2: merges =================
  if (blk < 64) {
    // merge 32 partial top-3s per target (plane-major, coalesced), block-sum
    const int idx = blk * 256 + tid;  // over cBN
    const float* plane = ws + OFF_T3;
    float t0 = FINF, t1 = FINF, t2 = FINF;
#pragma unroll 8
    for (int q = 0; q < cJC * 3; ++q)
      top3_insert(t0, t1, t2, plane[q * cBN + idx]);
    const float ht = ws[OFF_TGT4 + idx * 4 + 3];
    const float d0 = fmaxf(2.f * (t0 + ht), 0.f);
    const float d1 = fmaxf(2.f * (t1 + ht), 0.f);
    const float d2 = fmaxf(2.f * (t2 + ht), 0.f);
    const float s = block_sum(d0 + d1 + d2, red, tid);
    if (tid == 0) ws[OFF_GM + blk] = s;
  } else if (blk < 64 + 256) {
    // merge 16 chunk-mins per pred, add |p|^2, block-sum
    const int rb = blk - 64;
    const int b = rb >> 5;
    const int jb = rb & 31;
    const int j = jb * 256 + tid;  // 0..8191
    float contrib = 0.f;
    if (j < cJ) {
      float m = FINF;
#pragma unroll
      for (int nc = 0; nc < cNC; ++nc)
        m = fminf(m, ws[OFF_PSP + (b * cNC + nc) * cJPAD + j]);
      const float hp = ws[OFF_PRED4 + (b * cJ + j) * 4 + 3];
      contrib = fmaxf(2.f * (m + hp), 0.f);
    }
    const float s = block_sum(contrib, red, tid);
    if (tid == 0) ws[OFF_PS + b * 32 + jb] = s;
  }
  grid.sync();

  // ================= phase 3: centroids + repulsion + combine =================
  if (blk == 0) {
    if (tid < cB * cS) {
      const int bs = tid;
      const float* M = ws + OFF_SM + bs * 288;
      const float* vb = ws + OFF_VBAR;
      float c0 = ws[OFF_SC + bs * 3 + 0];
      float c1 = ws[OFF_SC + bs * 3 + 1];
      float c2 = ws[OFF_SC + bs * 3 + 2];
#pragma unroll 8
      for (int p = 0; p < cP; ++p) {
        const float* ob = ws + OFF_OBAR + p * 3;
        const float d0 = vb[0] + ob[0], d1 = vb[1] + ob[1], d2 = vb[2] + ob[2];
        c0 = fmaf(M[p * 9 + 0], d0, fmaf(M[p * 9 + 1], d1, fmaf(M[p * 9 + 2], d2, c0)));
        c1 = fmaf(M[p * 9 + 3], d0, fmaf(M[p * 9 + 4], d1, fmaf(M[p * 9 + 5], d2, c1)));
        c2 = fmaf(M[p * 9 + 6], d0, fmaf(M[p * 9 + 7], d1, fmaf(M[p * 9 + 8], d2, c2)));
      }
      scent[bs * 3 + 0] = c0;
      scent[bs * 3 + 1] = c1;
      scent[bs * 3 + 2] = c2;
    }
    __syncthreads();
    float acc = 0.f;
    for (int idx = tid; idx < cB * cS * cS; idx += 256) {
      const int b = idx / (cS * cS);
      const int r = idx % (cS * cS);
      const int i = r / cS, jj = r % cS;
      if (i == jj) continue;
      const float* ci = scent + (b * cS + i) * 3;
      const float* cj = scent + (b * cS + jj) * 3;
      const float dx = ci[0] - cj[0], dy = ci[1] - cj[1], dz = ci[2] - cj[2];
      const float d = sqrtf(fmaf(dx, dx, fmaf(dy, dy, dz * dz)));
      acc += expf(5.0f * fmaxf(0.5f - d, 0.0f));
    }
    const float repsum = block_sum(acc, red, tid);
    __syncthreads();
    const float gsum = block_sum((tid < 64) ? ws[OFF_GM + tid] : 0.f, red, tid);
    __syncthreads();
    const float pssum = block_sum(ws[OFF_PS + tid], red, tid);
    if (tid == 0) {
      const float global_loss = gsum / (float)(cB * cN * 3);
      const float per_slot = pssum / (float)(cB * cS * cK);
      const float rep = repsum / (float)(cB * cS * (cS - 1));
      out[0] = 0.7f * global_loss + 0.3f * per_slot + 0.2f * rep;
    }
  }
}

extern "C" void kernel_launch(void* const* d_in, const int* in_sizes, int n_in,
                              void* d_out, int out_size, void* d_ws, size_t ws_size,
                              hipStream_t stream) {
  const float* scales     = (const float*)d_in[0];
  const float* transforms = (const float*)d_in[1];
  const float* pw         = (const float*)d_in[2];
  const float* offs       = (const float*)d_in[3];
  const float* target     = (const float*)d_in[4];
  const float* verts      = (const float*)d_in[5];
  float* out = (float*)d_out;
  float* ws = (float*)d_ws;

  void* args[8] = {(void*)&scales, (void*)&transforms, (void*)&pw, (void*)&offs,
                   (void*)&verts, (void*)&target, (void*)&ws, (void*)&out};
  hipLaunchCooperativeKernel((const void*)k_mega, dim3(GRID), dim3(256), args, 0,
                             stream);
}

// Round 6
// 93.018 us; speedup vs baseline: 3.2686x; 3.2686x over previous
//
#include <hip/hip_runtime.h>
#include <math.h>

namespace {
constexpr int cB = 8, cS = 16, cP = 32, cN = 2048, cV = 2562;
constexpr int cK = 500;              // K_SAMPLE
constexpr int cJ = cS * cK;          // 8000 pred points per batch
constexpr int cJC = 32;              // j-chunks for global role (250 each)
constexpr int cJCH = cJ / cJC;       // 250
constexpr int cNC = 16;              // target-chunks for perslot role (128 each)
constexpr int cNCH = cN / cNC;       // 128
constexpr int cJPAD = 8192;
constexpr int cBN = cB * cN;         // 16384
constexpr float FINF = 3.402823466e+38f;

// workspace layout (float offsets)
constexpr int OFF_PRED4 = 0;                         // cB*cJ*4 = 256000
constexpr int OFF_TGT4  = 256000;                    // cBN*4 = 65536
constexpr int OFF_VBAR  = 321536;                    // 4
constexpr int OFF_OBAR  = 321540;                    // 96
constexpr int OFF_SM    = 321664;                    // 128*288 = 36864
constexpr int OFF_SC    = 358528;                    // 384
constexpr int OFF_T3    = 358912;                    // 96*cBN = 1572864 (plane-major)
constexpr int OFF_PSP   = 1931776;                   // cB*cNC*cJPAD = 1048576
constexpr int OFF_GM    = 2980352;                   // 64
constexpr int OFF_PS    = 2980416;                   // 256
constexpr int OFF_CNT   = 2980672;                   // 1 (uint)
constexpr int MERGE_BLOCKS = 64 + 256;
} // namespace

__device__ __forceinline__ float block_sum(float v, float* red, int tid) {
  red[tid] = v;
  __syncthreads();
  for (int s = 128; s > 0; s >>= 1) {
    if (tid < s) red[tid] += red[tid + s];
    __syncthreads();
  }
  return red[0];
}

// branchless sorted top-3 insert, 3 VALU ops (min + 2x med3); exact
__device__ __forceinline__ void top3_insert(float& t0, float& t1, float& t2, float d) {
  const float n1 = __builtin_amdgcn_fmed3f(t0, t1, d);
  const float n2 = __builtin_amdgcn_fmed3f(t1, t2, d);
  t0 = fminf(t0, d);
  t1 = n1;
  t2 = n2;
}

// ---------- kernel FRONT: role-split ----------
__global__ void __launch_bounds__(256) k_front(const float* __restrict__ scales,
                                               const float* __restrict__ transforms,
                                               const float* __restrict__ pw,
                                               const float* __restrict__ offs,
                                               const float* __restrict__ verts,
                                               const float* __restrict__ target,
                                               float* __restrict__ ws) {
  const int blk = blockIdx.x;
  const int tid = threadIdx.x;
  if (blk <= cP) {
    __shared__ float red[256];
    const float* src = (blk < cP) ? (offs + blk * cV * 3) : verts;
    float acc0 = 0.f, acc1 = 0.f, acc2 = 0.f;
    for (int v = tid; v < cV; v += 256) {
      acc0 += src[v * 3 + 0];
      acc1 += src[v * 3 + 1];
      acc2 += src[v * 3 + 2];
    }
    float* dst = (blk < cP) ? (ws + OFF_OBAR + blk * 3) : (ws + OFF_VBAR);
    float a[3] = {acc0, acc1, acc2};
    for (int c = 0; c < 3; ++c) {
      float s = block_sum(a[c], red, tid);
      if (tid == 0) dst[c] = s / (float)cV;
      __syncthreads();
    }
  } else if (blk <= cP + 64) {
    const int idx = (blk - (cP + 1)) * 256 + tid;  // over cBN
    const float x = target[idx * 3 + 0];
    const float y = target[idx * 3 + 1];
    const float z = target[idx * 3 + 2];
    ((float4*)(ws + OFF_TGT4))[idx] =
        make_float4(x, y, z, 0.5f * fmaf(x, x, fmaf(y, y, z * z)));
  } else {
    const int bs = blk - (cP + 65);  // 0..127
    __shared__ float sM[cP][9];
    __shared__ float sC[3];
    __shared__ float sWT[cP][3];
    if (tid < cP) {
      const int p = tid;
      const float* t = transforms + (bs * cP + p) * 6;
      const float w = pw[bs * cP + p];
      const float sc = scales[bs];
      const float a = t[3], b = t[4], c = t[5];
      const float ca = cosf(a), sa = sinf(a);
      const float cb = cosf(b), sb = sinf(b);
      const float cg = cosf(c), sg = sinf(c);
      const float f = w * sc;
      sM[p][0] = f * (cb * cg);
      sM[p][1] = f * (-cb * sg);
      sM[p][2] = f * (sb);
      sM[p][3] = f * (ca * sg + sa * sb * cg);
      sM[p][4] = f * (ca * cg - sa * sb * sg);
      sM[p][5] = f * (-sa * cb);
      sM[p][6] = f * (sa * sg - ca * sb * cg);
      sM[p][7] = f * (sa * cg + ca * sb * sg);
      sM[p][8] = f * (ca * cb);
      sWT[p][0] = w * t[0];
      sWT[p][1] = w * t[1];
      sWT[p][2] = w * t[2];
    }
    __syncthreads();
    if (tid < 3) {
      float s = 0.f;
      for (int p = 0; p < cP; ++p) s += sWT[p][tid];
      sC[tid] = s;
    }
    __syncthreads();
    if (tid < cP * 9) ws[OFF_SM + bs * 288 + tid] = ((const float*)sM)[tid];
    if (tid < 3) ws[OFF_SC + bs * 3 + tid] = sC[tid];
    for (int k = tid; k < cK; k += 256) {
      const float x0 = verts[k * 3 + 0], x1 = verts[k * 3 + 1], x2 = verts[k * 3 + 2];
      float a0 = sC[0], a1 = sC[1], a2 = sC[2];
#pragma unroll 8
      for (int p = 0; p < cP; ++p) {
        const float* o = offs + (p * cV + k) * 3;
        const float d0 = x0 + o[0], d1 = x1 + o[1], d2 = x2 + o[2];
        a0 = fmaf(sM[p][0], d0, fmaf(sM[p][1], d1, fmaf(sM[p][2], d2, a0)));
        a1 = fmaf(sM[p][3], d0, fmaf(sM[p][4], d1, fmaf(sM[p][5], d2, a1)));
        a2 = fmaf(sM[p][6], d0, fmaf(sM[p][7], d1, fmaf(sM[p][8], d2, a2)));
      }
      ((float4*)(ws + OFF_PRED4))[bs * cK + k] =
          make_float4(a0, a1, a2, 0.5f * fmaf(a0, a0, fmaf(a1, a1, a2 * a2)));
    }
  }
}

// ---------- kernel DIST: fused role-split distance pass (768 blocks) ----------
// blk%3==0 : global role (256 blocks). 250-pred LDS tile, 8 targets/thread.
// else     : perslot role (512 blocks). 128-target LDS tile, 8 preds/thread.
// blk%3 mix puts 1 global + 2 perslot block on each CU (round-robin dispatch).
__global__ void __launch_bounds__(256) k_dist(float* __restrict__ ws) {
  __shared__ float4 sBuf[cJCH];  // 4000 B
  const int blk = blockIdx.x;
  const int tid = threadIdx.x;
  if (blk == 0 && tid == 0) ((unsigned*)(ws + OFF_CNT))[0] = 0u;  // reset merge counter
  if (blk % 3 == 0) {
    const int g = blk / 3;       // 0..255
    const int b = g & 7;
    const int jc = g >> 3;       // 0..31
    const float4* pr = (const float4*)(ws + OFF_PRED4) + b * cJ + jc * cJCH;
    if (tid < cJCH) sBuf[tid] = pr[tid];
    __syncthreads();
    const float4* tg = (const float4*)(ws + OFF_TGT4) + b * cN;
    float4 t[8];
#pragma unroll
    for (int q = 0; q < 8; ++q) t[q] = tg[tid + q * 256];
    float a0[8], a1[8], a2[8];
#pragma unroll
    for (int q = 0; q < 8; ++q) { a0[q] = FINF; a1[q] = FINF; a2[q] = FINF; }
#pragma unroll 2
    for (int j = 0; j < cJCH; ++j) {
      const float4 p = sBuf[j];
#pragma unroll
      for (int q = 0; q < 8; ++q) {
        const float s =
            fmaf(-t[q].x, p.x, fmaf(-t[q].y, p.y, fmaf(-t[q].z, p.z, p.w)));
        top3_insert(a0[q], a1[q], a2[q], s);
      }
    }
    float* plane = ws + OFF_T3 + (jc * 3) * cBN;
#pragma unroll
    for (int q = 0; q < 8; ++q) {
      const int idx = b * cN + tid + q * 256;
      plane[0 * cBN + idx] = a0[q];
      plane[1 * cBN + idx] = a1[q];
      plane[2 * cBN + idx] = a2[q];
    }
  } else {
    const int idxr = (blk / 3) * 2 + (blk % 3) - 1;  // 0..511
    const int jb = idxr & 3;
    const int nc = (idxr >> 2) & 15;
    const int b = idxr >> 6;
    const float4* tg = (const float4*)(ws + OFF_TGT4) + b * cN + nc * cNCH;
    if (tid < cNCH) sBuf[tid] = tg[tid];
    __syncthreads();
    const float4* pr = (const float4*)(ws + OFF_PRED4) + b * cJ;
    float px[8], py[8], pz[8];
    float m[8] = {FINF, FINF, FINF, FINF, FINF, FINF, FINF, FINF};
#pragma unroll
    for (int q = 0; q < 8; ++q) {
      int j = jb * 2048 + q * 256 + tid;
      j = (j < cJ) ? j : (cJ - 1);
      const float4 p = pr[j];
      px[q] = p.x; py[q] = p.y; pz[q] = p.z;
    }
#pragma unroll 2
    for (int n = 0; n < cNCH; ++n) {
      const float4 t = sBuf[n];
#pragma unroll
      for (int q = 0; q < 8; ++q) {
        const float s = fmaf(-px[q], t.x, fmaf(-py[q], t.y, fmaf(-pz[q], t.z, t.w)));
        m[q] = fminf(m[q], s);
      }
    }
    float* o = ws + OFF_PSP + (b * cNC + nc) * cJPAD + jb * 2048 + tid;
#pragma unroll
    for (int q = 0; q < 8; ++q) o[q * 256] = m[q];
  }
}

// ---------- kernel MERGE: role-split partial merges + last-block finale ----------
__global__ void __launch_bounds__(256) k_merge(float* __restrict__ ws,
                                               float* __restrict__ out) {
  __shared__ float red[256];
  __shared__ float scent[cB * cS * 3];
  __shared__ bool sLast;
  const int blk = blockIdx.x;
  const int tid = threadIdx.x;
  if (blk < 64) {
    // merge 32 partial top-3s per target (plane-major, coalesced), block-sum
    const int idx = blk * 256 + tid;  // over cBN
    const float* plane = ws + OFF_T3;
    float t0 = FINF, t1 = FINF, t2 = FINF;
#pragma unroll 8
    for (int q = 0; q < cJC * 3; ++q)
      top3_insert(t0, t1, t2, plane[q * cBN + idx]);
    const float ht = ws[OFF_TGT4 + idx * 4 + 3];
    const float d0 = fmaxf(2.f * (t0 + ht), 0.f);
    const float d1 = fmaxf(2.f * (t1 + ht), 0.f);
    const float d2 = fmaxf(2.f * (t2 + ht), 0.f);
    const float s = block_sum(d0 + d1 + d2, red, tid);
    if (tid == 0) ws[OFF_GM + blk] = s;
  } else {
    // merge 16 chunk-mins per pred, add |p|^2, block-sum
    const int rb = blk - 64;
    const int b = rb >> 5;
    const int jb = rb & 31;
    const int j = jb * 256 + tid;  // 0..8191
    float contrib = 0.f;
    if (j < cJ) {
      float m = FINF;
#pragma unroll
      for (int nc = 0; nc < cNC; ++nc)
        m = fminf(m, ws[OFF_PSP + (b * cNC + nc) * cJPAD + j]);
      const float hp = ws[OFF_PRED4 + (b * cJ + j) * 4 + 3];
      contrib = fmaxf(2.f * (m + hp), 0.f);
    }
    const float s = block_sum(contrib, red, tid);
    if (tid == 0) ws[OFF_PS + b * 32 + jb] = s;
  }
  // ---- last-block finale (deterministic: reads fixed arrays in fixed order) ----
  __threadfence();
  if (tid == 0) {
    const unsigned v = atomicAdd((unsigned*)(ws + OFF_CNT), 1u);
    sLast = (v == MERGE_BLOCKS - 1);
  }
  __syncthreads();
  if (!sLast) return;
  __threadfence();
  if (tid < cB * cS) {
    const int bs = tid;
    const float* M = ws + OFF_SM + bs * 288;
    const float* vb = ws + OFF_VBAR;
    float c0 = ws[OFF_SC + bs * 3 + 0];
    float c1 = ws[OFF_SC + bs * 3 + 1];
    float c2 = ws[OFF_SC + bs * 3 + 2];
#pragma unroll 8
    for (int p = 0; p < cP; ++p) {
      const float* ob = ws + OFF_OBAR + p * 3;
      const float d0 = vb[0] + ob[0], d1 = vb[1] + ob[1], d2 = vb[2] + ob[2];
      c0 = fmaf(M[p * 9 + 0], d0, fmaf(M[p * 9 + 1], d1, fmaf(M[p * 9 + 2], d2, c0)));
      c1 = fmaf(M[p * 9 + 3], d0, fmaf(M[p * 9 + 4], d1, fmaf(M[p * 9 + 5], d2, c1)));
      c2 = fmaf(M[p * 9 + 6], d0, fmaf(M[p * 9 + 7], d1, fmaf(M[p * 9 + 8], d2, c2)));
    }
    scent[bs * 3 + 0] = c0;
    scent[bs * 3 + 1] = c1;
    scent[bs * 3 + 2] = c2;
  }
  __syncthreads();
  float acc = 0.f;
  for (int idx = tid; idx < cB * cS * cS; idx += 256) {
    const int b = idx / (cS * cS);
    const int r = idx % (cS * cS);
    const int i = r / cS, jj = r % cS;
    if (i == jj) continue;
    const float* ci = scent + (b * cS + i) * 3;
    const float* cj = scent + (b * cS + jj) * 3;
    const float dx = ci[0] - cj[0], dy = ci[1] - cj[1], dz = ci[2] - cj[2];
    const float d = sqrtf(fmaf(dx, dx, fmaf(dy, dy, dz * dz)));
    acc += expf(5.0f * fmaxf(0.5f - d, 0.0f));
  }
  const float repsum = block_sum(acc, red, tid);
  __syncthreads();
  const float gsum = block_sum((tid < 64) ? ws[OFF_GM + tid] : 0.f, red, tid);
  __syncthreads();
  const float pssum = block_sum(ws[OFF_PS + tid], red, tid);
  if (tid == 0) {
    const float global_loss = gsum / (float)(cB * cN * 3);
    const float per_slot = pssum / (float)(cB * cS * cK);
    const float rep = repsum / (float)(cB * cS * (cS - 1));
    out[0] = 0.7f * global_loss + 0.3f * per_slot + 0.2f * rep;
  }
}

extern "C" void kernel_launch(void* const* d_in, const int* in_sizes, int n_in,
                              void* d_out, int out_size, void* d_ws, size_t ws_size,
                              hipStream_t stream) {
  const float* scales     = (const float*)d_in[0];
  const float* transforms = (const float*)d_in[1];
  const float* pw         = (const float*)d_in[2];
  const float* offs       = (const float*)d_in[3];
  const float* target     = (const float*)d_in[4];
  const float* verts      = (const float*)d_in[5];
  float* out = (float*)d_out;
  float* ws = (float*)d_ws;

  k_front<<<cP + 1 + 64 + cB * cS, 256, 0, stream>>>(scales, transforms, pw, offs,
                                                     verts, target, ws);
  k_dist<<<768, 256, 0, stream>>>(ws);
  k_merge<<<MERGE_BLOCKS, 256, 0, stream>>>(ws, out);
}

// Round 7
// 72.152 us; speedup vs baseline: 4.2139x; 1.2892x over previous
//
#include <hip/hip_runtime.h>
#include <math.h>

namespace {
constexpr int cB = 8, cS = 16, cP = 32, cN = 2048, cV = 2562;
constexpr int cK = 500;              // K_SAMPLE
constexpr int cJ = cS * cK;          // 8000 pred points per batch
constexpr int cJC = 64;              // j-chunks for global role (125 each)
constexpr int cJCH = cJ / cJC;       // 125
constexpr int cNC = 16;              // target-chunks for perslot role (128 each)
constexpr int cNCH = cN / cNC;       // 128
constexpr int cJPAD = 8192;
constexpr int cBN = cB * cN;         // 16384
constexpr float FINF = 3.402823466e+38f;

// workspace layout (float offsets)
constexpr int OFF_PRED4 = 0;                         // cB*cJ*4 = 256000
constexpr int OFF_TGT4  = 256000;                    // cBN*4 = 65536
constexpr int OFF_VBAR  = 321536;                    // 4
constexpr int OFF_OBAR  = 321540;                    // 96
constexpr int OFF_SM    = 321664;                    // 128*288 = 36864
constexpr int OFF_SC    = 358528;                    // 384
constexpr int OFF_T3    = 358912;                    // 192*cBN = 3145728 (plane-major)
constexpr int OFF_PSP   = 3504640;                   // cB*cNC*cJPAD = 1048576
constexpr int OFF_GM    = 4553216;                   // 64
constexpr int OFF_PS    = 4553280;                   // 256
} // namespace

__device__ __forceinline__ float block_sum(float v, float* red, int tid) {
  red[tid] = v;
  __syncthreads();
  for (int s = 128; s > 0; s >>= 1) {
    if (tid < s) red[tid] += red[tid + s];
    __syncthreads();
  }
  return red[0];
}

// branchless sorted top-3 insert, 3 VALU ops (min + 2x med3); exact
__device__ __forceinline__ void top3_insert(float& t0, float& t1, float& t2, float d) {
  const float n1 = __builtin_amdgcn_fmed3f(t0, t1, d);
  const float n2 = __builtin_amdgcn_fmed3f(t1, t2, d);
  t0 = fminf(t0, d);
  t1 = n1;
  t2 = n2;
}

// ---------- kernel FRONT: role-split ----------
__global__ void __launch_bounds__(256) k_front(const float* __restrict__ scales,
                                               const float* __restrict__ transforms,
                                               const float* __restrict__ pw,
                                               const float* __restrict__ offs,
                                               const float* __restrict__ verts,
                                               const float* __restrict__ target,
                                               float* __restrict__ ws) {
  const int blk = blockIdx.x;
  const int tid = threadIdx.x;
  if (blk <= cP) {
    __shared__ float red[256];
    const float* src = (blk < cP) ? (offs + blk * cV * 3) : verts;
    float acc0 = 0.f, acc1 = 0.f, acc2 = 0.f;
    for (int v = tid; v < cV; v += 256) {
      acc0 += src[v * 3 + 0];
      acc1 += src[v * 3 + 1];
      acc2 += src[v * 3 + 2];
    }
    float* dst = (blk < cP) ? (ws + OFF_OBAR + blk * 3) : (ws + OFF_VBAR);
    float a[3] = {acc0, acc1, acc2};
    for (int c = 0; c < 3; ++c) {
      float s = block_sum(a[c], red, tid);
      if (tid == 0) dst[c] = s / (float)cV;
      __syncthreads();
    }
  } else if (blk <= cP + 64) {
    const int idx = (blk - (cP + 1)) * 256 + tid;  // over cBN
    const float x = target[idx * 3 + 0];
    const float y = target[idx * 3 + 1];
    const float z = target[idx * 3 + 2];
    ((float4*)(ws + OFF_TGT4))[idx] =
        make_float4(x, y, z, 0.5f * fmaf(x, x, fmaf(y, y, z * z)));
  } else {
    const int bs = blk - (cP + 65);  // 0..127
    __shared__ float sM[cP][9];
    __shared__ float sC[3];
    __shared__ float sWT[cP][3];
    if (tid < cP) {
      const int p = tid;
      const float* t = transforms + (bs * cP + p) * 6;
      const float w = pw[bs * cP + p];
      const float sc = scales[bs];
      const float a = t[3], b = t[4], c = t[5];
      const float ca = cosf(a), sa = sinf(a);
      const float cb = cosf(b), sb = sinf(b);
      const float cg = cosf(c), sg = sinf(c);
      const float f = w * sc;
      sM[p][0] = f * (cb * cg);
      sM[p][1] = f * (-cb * sg);
      sM[p][2] = f * (sb);
      sM[p][3] = f * (ca * sg + sa * sb * cg);
      sM[p][4] = f * (ca * cg - sa * sb * sg);
      sM[p][5] = f * (-sa * cb);
      sM[p][6] = f * (sa * sg - ca * sb * cg);
      sM[p][7] = f * (sa * cg + ca * sb * sg);
      sM[p][8] = f * (ca * cb);
      sWT[p][0] = w * t[0];
      sWT[p][1] = w * t[1];
      sWT[p][2] = w * t[2];
    }
    __syncthreads();
    if (tid < 3) {
      float s = 0.f;
      for (int p = 0; p < cP; ++p) s += sWT[p][tid];
      sC[tid] = s;
    }
    __syncthreads();
    if (tid < cP * 9) ws[OFF_SM + bs * 288 + tid] = ((const float*)sM)[tid];
    if (tid < 3) ws[OFF_SC + bs * 3 + tid] = sC[tid];
    for (int k = tid; k < cK; k += 256) {
      const float x0 = verts[k * 3 + 0], x1 = verts[k * 3 + 1], x2 = verts[k * 3 + 2];
      float a0 = sC[0], a1 = sC[1], a2 = sC[2];
#pragma unroll 8
      for (int p = 0; p < cP; ++p) {
        const float* o = offs + (p * cV + k) * 3;
        const float d0 = x0 + o[0], d1 = x1 + o[1], d2 = x2 + o[2];
        a0 = fmaf(sM[p][0], d0, fmaf(sM[p][1], d1, fmaf(sM[p][2], d2, a0)));
        a1 = fmaf(sM[p][3], d0, fmaf(sM[p][4], d1, fmaf(sM[p][5], d2, a1)));
        a2 = fmaf(sM[p][6], d0, fmaf(sM[p][7], d1, fmaf(sM[p][8], d2, a2)));
      }
      ((float4*)(ws + OFF_PRED4))[bs * cK + k] =
          make_float4(a0, a1, a2, 0.5f * fmaf(a0, a0, fmaf(a1, a1, a2 * a2)));
    }
  }
}

// ---------- kernel DIST: fused role-split distance pass (1024 blocks, 4/CU) ----------
// role = (blk + blk/256) & 1 : alternates per CU under 256-stride round-robin.
// global role (512 blocks): 125-pred LDS tile, 8 targets/thread, top-3 of s.
// perslot role (512 blocks): 128-target LDS tile, 8 preds/thread, min of s.
__global__ void __launch_bounds__(256, 4) k_dist(float* __restrict__ ws) {
  __shared__ float4 sBuf[cNCH];  // 2048 B (global role uses first 125)
  const int blk = blockIdx.x;
  const int tid = threadIdx.x;
  const int rnd = blk >> 8;            // 0..3
  const int lane = blk & 255;
  const int role = (lane + rnd) & 1;
  const int sub = rnd * 128 + (lane >> 1);  // 0..511 within role
  if (role == 0) {
    // global role
    const int b = sub & 7;
    const int jc = sub >> 3;       // 0..63
    const float4* pr = (const float4*)(ws + OFF_PRED4) + b * cJ + jc * cJCH;
    if (tid < cJCH) sBuf[tid] = pr[tid];
    __syncthreads();
    const float4* tg = (const float4*)(ws + OFF_TGT4) + b * cN;
    float4 t[8];
#pragma unroll
    for (int q = 0; q < 8; ++q) t[q] = tg[tid + q * 256];
    float a0[8], a1[8], a2[8];
#pragma unroll
    for (int q = 0; q < 8; ++q) { a0[q] = FINF; a1[q] = FINF; a2[q] = FINF; }
    for (int j = 0; j < cJCH; ++j) {
      const float4 p = sBuf[j];
#pragma unroll
      for (int q = 0; q < 8; ++q) {
        const float s =
            fmaf(-t[q].x, p.x, fmaf(-t[q].y, p.y, fmaf(-t[q].z, p.z, p.w)));
        top3_insert(a0[q], a1[q], a2[q], s);
      }
    }
    float* plane = ws + OFF_T3 + (jc * 3) * cBN;
#pragma unroll
    for (int q = 0; q < 8; ++q) {
      const int idx = b * cN + tid + q * 256;
      plane[0 * cBN + idx] = a0[q];
      plane[1 * cBN + idx] = a1[q];
      plane[2 * cBN + idx] = a2[q];
    }
  } else {
    // perslot role
    const int jb = sub & 3;
    const int nc = (sub >> 2) & 15;
    const int b = sub >> 6;
    const float4* tg = (const float4*)(ws + OFF_TGT4) + b * cN + nc * cNCH;
    if (tid < cNCH) sBuf[tid] = tg[tid];
    __syncthreads();
    const float4* pr = (const float4*)(ws + OFF_PRED4) + b * cJ;
    float px[8], py[8], pz[8];
    float m[8] = {FINF, FINF, FINF, FINF, FINF, FINF, FINF, FINF};
#pragma unroll
    for (int q = 0; q < 8; ++q) {
      int j = jb * 2048 + q * 256 + tid;
      j = (j < cJ) ? j : (cJ - 1);
      const float4 p = pr[j];
      px[q] = p.x; py[q] = p.y; pz[q] = p.z;
    }
#pragma unroll 2
    for (int n = 0; n < cNCH; ++n) {
      const float4 t = sBuf[n];
#pragma unroll
      for (int q = 0; q < 8; ++q) {
        const float s = fmaf(-px[q], t.x, fmaf(-py[q], t.y, fmaf(-pz[q], t.z, t.w)));
        m[q] = fminf(m[q], s);
      }
    }
    float* o = ws + OFF_PSP + (b * cNC + nc) * cJPAD + jb * 2048 + tid;
#pragma unroll
    for (int q = 0; q < 8; ++q) o[q * 256] = m[q];
  }
}

// ---------- kernel MERGE: role-split partial merges ----------
// blk 0..63   : merge 64 partial top-3s per target (plane-major, coalesced), block-sum
// blk 64..319 : merge 16 chunk-mins per pred, add |p|^2, block-sum
__global__ void __launch_bounds__(256) k_merge(float* __restrict__ ws) {
  __shared__ float red[256];
  const int blk = blockIdx.x;
  const int tid = threadIdx.x;
  if (blk < 64) {
    const int idx = blk * 256 + tid;  // over cBN
    const float* plane = ws + OFF_T3;
    float t0 = FINF, t1 = FINF, t2 = FINF;
#pragma unroll 8
    for (int q = 0; q < cJC * 3; ++q)
      top3_insert(t0, t1, t2, plane[q * cBN + idx]);
    const float ht = ws[OFF_TGT4 + idx * 4 + 3];
    const float d0 = fmaxf(2.f * (t0 + ht), 0.f);
    const float d1 = fmaxf(2.f * (t1 + ht), 0.f);
    const float d2 = fmaxf(2.f * (t2 + ht), 0.f);
    const float s = block_sum(d0 + d1 + d2, red, tid);
    if (tid == 0) ws[OFF_GM + blk] = s;
  } else {
    const int rb = blk - 64;
    const int b = rb >> 5;
    const int jb = rb & 31;
    const int j = jb * 256 + tid;  // 0..8191
    float contrib = 0.f;
    if (j < cJ) {
      float m = FINF;
#pragma unroll
      for (int nc = 0; nc < cNC; ++nc)
        m = fminf(m, ws[OFF_PSP + (b * cNC + nc) * cJPAD + j]);
      const float hp = ws[OFF_PRED4 + (b * cJ + j) * 4 + 3];
      contrib = fmaxf(2.f * (m + hp), 0.f);
    }
    const float s = block_sum(contrib, red, tid);
    if (tid == 0) ws[OFF_PS + b * 32 + jb] = s;
  }
}

// ---------- kernel F: centroids + repulsion + combine ----------
__global__ void __launch_bounds__(256) k_final(float* __restrict__ ws, float* __restrict__ out) {
  __shared__ float red[256];
  __shared__ float scent[cB * cS * 3];
  const int tid = threadIdx.x;
  if (tid < cB * cS) {
    const int bs = tid;
    const float* M = ws + OFF_SM + bs * 288;
    const float* vb = ws + OFF_VBAR;
    float c0 = ws[OFF_SC + bs * 3 + 0];
    float c1 = ws[OFF_SC + bs * 3 + 1];
    float c2 = ws[OFF_SC + bs * 3 + 2];
#pragma unroll 8
    for (int p = 0; p < cP; ++p) {
      const float* ob = ws + OFF_OBAR + p * 3;
      const float d0 = vb[0] + ob[0], d1 = vb[1] + ob[1], d2 = vb[2] + ob[2];
      c0 = fmaf(M[p * 9 + 0], d0, fmaf(M[p * 9 + 1], d1, fmaf(M[p * 9 + 2], d2, c0)));
      c1 = fmaf(M[p * 9 + 3], d0, fmaf(M[p * 9 + 4], d1, fmaf(M[p * 9 + 5], d2, c1)));
      c2 = fmaf(M[p * 9 + 6], d0, fmaf(M[p * 9 + 7], d1, fmaf(M[p * 9 + 8], d2, c2)));
    }
    scent[bs * 3 + 0] = c0;
    scent[bs * 3 + 1] = c1;
    scent[bs * 3 + 2] = c2;
  }
  __syncthreads();
  float acc = 0.f;
  for (int idx = tid; idx < cB * cS * cS; idx += 256) {
    const int b = idx / (cS * cS);
    const int r = idx % (cS * cS);
    const int i = r / cS, jj = r % cS;
    if (i == jj) continue;
    const float* ci = scent + (b * cS + i) * 3;
    const float* cj = scent + (b * cS + jj) * 3;
    const float dx = ci[0] - cj[0], dy = ci[1] - cj[1], dz = ci[2] - cj[2];
    const float d = sqrtf(fmaf(dx, dx, fmaf(dy, dy, dz * dz)));
    acc += expf(5.0f * fmaxf(0.5f - d, 0.0f));
  }
  const float repsum = block_sum(acc, red, tid);
  __syncthreads();
  const float gsum = block_sum((tid < 64) ? ws[OFF_GM + tid] : 0.f, red, tid);
  __syncthreads();
  const float pssum = block_sum(ws[OFF_PS + tid], red, tid);
  if (tid == 0) {
    const float global_loss = gsum / (float)(cB * cN * 3);
    const float per_slot = pssum / (float)(cB * cS * cK);
    const float rep = repsum / (float)(cB * cS * (cS - 1));
    out[0] = 0.7f * global_loss + 0.3f * per_slot + 0.2f * rep;
  }
}

extern "C" void kernel_launch(void* const* d_in, const int* in_sizes, int n_in,
                              void* d_out, int out_size, void* d_ws, size_t ws_size,
                              hipStream_t stream) {
  const float* scales     = (const float*)d_in[0];
  const float* transforms = (const float*)d_in[1];
  const float* pw         = (const float*)d_in[2];
  const float* offs       = (const float*)d_in[3];
  const float* target     = (const float*)d_in[4];
  const float* verts      = (const float*)d_in[5];
  float* out = (float*)d_out;
  float* ws = (float*)d_ws;

  k_front<<<cP + 1 + 64 + cB * cS, 256, 0, stream>>>(scales, transforms, pw, offs,
                                                     verts, target, ws);
  k_dist<<<1024, 256, 0, stream>>>(ws);
  k_merge<<<64 + 256, 256, 0, stream>>>(ws);
  k_final<<<1, 256, 0, stream>>>(ws, out);
}